// Round 11
// baseline (255.629 us; speedup 1.0000x reference)
//
#include <hip/hip_runtime.h>
#include <cstdint>
#include <cstddef>

typedef _Float16 half_t;
typedef _Float16 half8 __attribute__((ext_vector_type(8)));
typedef _Float16 half4v __attribute__((ext_vector_type(4)));
typedef float float4_ __attribute__((ext_vector_type(4)));

#define NB 8
#define SEQ 2048
#define DIM 256
#define NROWS (NB*SEQ)   // 16384
#define KS 4             // k-split -> grid 512 = 2 blocks/CU
#define NIT 16           // (2048/KS)/32 key-tiles per block

// async global->LDS DMA, 16B per lane; LDS dest = wave-uniform base + lane*16
__device__ __forceinline__ void dma16(const half_t* g, half_t* l) {
    __builtin_amdgcn_global_load_lds(
        (const __attribute__((address_space(1))) void*)g,
        (__attribute__((address_space(3))) void*)l,
        16, 0, 0);
}

// ---------------------------------------------------------------------------
// Kernel 1: fold M = Wq^T @ Wa; scores = (x M^T + bq2)·k^T (+ softmax-
// invariant const row, dropped). fp16 hi/lo planes, written PRE-SWIZZLED in
// the linear-kernel LDS image order (col m -> pos ((m>>3)^(d&7))*8 + (m&7))
// so linear can stage them with identity global_load_lds DMA.
// Also zeroes the attn combine tickets (block 0).
// ---------------------------------------------------------------------------
__global__ __launch_bounds__(256) void prep_kernel(
    const float* __restrict__ Wq, const float* __restrict__ Wk,
    const float* __restrict__ Wv, const float* __restrict__ Wa,
    const float* __restrict__ bq,
    half_t* __restrict__ M_hi, half_t* __restrict__ M_lo,
    half_t* __restrict__ Wk_hi, half_t* __restrict__ Wk_lo,
    half_t* __restrict__ Wv_hi, float* __restrict__ bq2,
    int* __restrict__ tickets)
{
    __shared__ float sWa[256];     // Wa[:,d]
    __shared__ float sred[256];    // bq2 reduction scratch
    const int d = blockIdx.x;      // q2 out-dim (row)
    const int m = threadIdx.x;     // in-dim (col)
    if (d == 0 && m < 128) tickets[m] = 0;   // attn combine tickets
    sWa[m] = Wa[m * 256 + d];      // one-time column gather
    __syncthreads();

    float a0 = 0.f, a1 = 0.f, a2 = 0.f, a3 = 0.f;
    #pragma unroll 8
    for (int e = 0; e < 256; e += 4) {
        a0 += sWa[e + 0] * Wq[(e + 0) * 256 + m];
        a1 += sWa[e + 1] * Wq[(e + 1) * 256 + m];
        a2 += sWa[e + 2] * Wq[(e + 2) * 256 + m];
        a3 += sWa[e + 3] * Wq[(e + 3) * 256 + m];
    }
    float acc = (a0 + a1) + (a2 + a3);

    // swizzled position within row d (XOR involution; matches linear's reads)
    const int pos  = (((m >> 3) ^ (d & 7)) << 3) | (m & 7);
    const int sidx = d * 256 + pos;
    const int idx  = d * 256 + m;

    half_t h = (half_t)acc;
    M_hi[sidx] = h;
    M_lo[sidx] = (half_t)(acc - (float)h);
    float wk = Wk[idx];
    h = (half_t)wk;
    Wk_hi[sidx] = h;
    Wk_lo[sidx] = (half_t)(wk - (float)h);
    Wv_hi[sidx] = (half_t)Wv[idx];

    // bq2[d] = sum_e bq[e]*Wa[e,d] -- parallel tree reduction
    sred[m] = bq[m] * sWa[m];
    __syncthreads();
    #pragma unroll
    for (int s = 128; s > 0; s >>= 1) {
        if (m < s) sred[m] += sred[m + s];
        __syncthreads();
    }
    if (m == 0) bq2[d] = sred[0];
}

// ---------------------------------------------------------------------------
// Kernel 2: linears (hi/lo numerics). Weight staging now via global_load_lds
// identity DMA from the pre-swizzled planes (no VALU/register round-trip).
// seg0: q2 = x@M^T+bq2, hi out, row-major. seg1: k, hi out, tile-swizzled.
// seg2: v -> vT tile-swizzled + key-permuted for reg-P PV.
// ---------------------------------------------------------------------------
__global__ __launch_bounds__(256, 2) void linear_kernel(
    const float* __restrict__ x, const float* __restrict__ states,
    const half_t* __restrict__ M_hi, const half_t* __restrict__ M_lo, const float* __restrict__ bq2,
    const half_t* __restrict__ Wk_hi, const half_t* __restrict__ Wk_lo, const float* __restrict__ bk,
    const half_t* __restrict__ Wv_hi, const float* __restrict__ bv,
    half_t* __restrict__ q2_hi,
    half_t* __restrict__ k_hi,
    half_t* __restrict__ vT)
{
    __shared__ half_t sB[2 * 64 * 256];   // weights hi+lo = 64 KiB; reused as repack buf
    half_t* sBh = sB;
    half_t* sBl = sB + 64 * 256;

    const int seg  = blockIdx.x >> 8;      // 0:q2 1:k 2:v
    const int t    = blockIdx.x & 255;
    const int tid  = threadIdx.x;
    const int lane = tid & 63;
    const int wv   = tid >> 6;
    const int quad = lane >> 4;
    const int l15  = lane & 15;
    const int rb   = t * 64;               // block row base
    const int r0   = rb + wv * 16;         // wave's 16 rows

    const float* src  = (seg == 0) ? x : states;
    const half_t* Bh  = (seg == 0) ? M_hi : (seg == 1) ? Wk_hi : Wv_hi;
    const half_t* Bl  = (seg == 0) ? M_lo : Wk_lo;
    const float* bias = (seg == 0) ? bq2 : (seg == 1) ? bk : bv;

    // A-frags direct from global: A[m=l15 -> row][k=c*32+quad*8+j], hi/lo split
    half8 ah[8], al[8];
    #pragma unroll
    for (int c = 0; c < 8; ++c) {
        const float* pa = src + (size_t)(r0 + l15) * 256 + c * 32 + quad * 8;
        float4_ u0 = *(const float4_*)pa;
        float4_ u1 = *(const float4_*)(pa + 4);
        #pragma unroll
        for (int j = 0; j < 4; ++j) {
            half_t hh = (half_t)u0[j];
            ah[c][j] = hh; al[c][j] = (half_t)(u0[j] - (float)hh);
            hh = (half_t)u1[j];
            ah[c][4 + j] = hh; al[c][4 + j] = (half_t)(u1[j] - (float)hh);
        }
    }

    float4_ acc[16];
    if (seg != 2) {
        #pragma unroll
        for (int nt = 0; nt < 16; ++nt) {
            float be = bias[nt * 16 + l15];
            acc[nt] = {be, be, be, be};
        }
    } else {
        #pragma unroll
        for (int et = 0; et < 16; ++et)
            #pragma unroll
            for (int r = 0; r < 4; ++r)
                acc[et][r] = bias[et * 16 + quad * 4 + r];
    }

    #pragma unroll
    for (int eg = 0; eg < 4; ++eg) {
        __syncthreads();   // previous e-group reads complete
        // stage weights e-group [64 e][256 k] via identity DMA (pre-swizzled)
        {
            const half_t* src_h = Bh + (size_t)eg * 16384;
            #pragma unroll
            for (int i = 0; i < 8; ++i) {
                const int sg = i * 4 + wv;            // 32 segments of 1 KiB
                dma16(src_h + sg * 512 + lane * 8, sBh + sg * 512);
            }
            if (seg != 2) {
                const half_t* src_l = Bl + (size_t)eg * 16384;
                #pragma unroll
                for (int i = 0; i < 8; ++i) {
                    const int sg = i * 4 + wv;
                    dma16(src_l + sg * 512 + lane * 8, sBl + sg * 512);
                }
            }
        }
        __syncthreads();   // vmcnt(0)+barrier: tile visible

        if (seg != 2) {
            #pragma unroll
            for (int ntl = 0; ntl < 4; ++ntl) {
                float4_ a = acc[eg * 4 + ntl];
                const int el = ntl * 16 + l15;
                #pragma unroll
                for (int c = 0; c < 8; ++c) {
                    int off = el * 256 + (((c * 4 + quad) ^ (el & 7)) * 8);
                    half8 bh = *(const half8*)(sBh + off);
                    half8 bl = *(const half8*)(sBl + off);
                    a = __builtin_amdgcn_mfma_f32_16x16x32_f16(ah[c], bh, a, 0, 0, 0);
                    a = __builtin_amdgcn_mfma_f32_16x16x32_f16(al[c], bh, a, 0, 0, 0);
                    a = __builtin_amdgcn_mfma_f32_16x16x32_f16(ah[c], bl, a, 0, 0, 0);
                }
                acc[eg * 4 + ntl] = a;
            }
        } else {
            // flipped: A = Wv tile (rows e), B = x rows -> D[e][row]
            #pragma unroll
            for (int ntl = 0; ntl < 4; ++ntl) {
                float4_ a = acc[eg * 4 + ntl];
                const int el = ntl * 16 + l15;
                #pragma unroll
                for (int c = 0; c < 8; ++c) {
                    int off = el * 256 + (((c * 4 + quad) ^ (el & 7)) * 8);
                    half8 aw = *(const half8*)(sBh + off);
                    a = __builtin_amdgcn_mfma_f32_16x16x32_f16(aw, ah[c], a, 0, 0, 0);
                }
                acc[eg * 4 + ntl] = a;
            }
        }
    }

    // epilogue: repack through LDS for coalesced half8 global stores
    __syncthreads();   // weights LDS no longer needed
    if (seg != 2) {
        half_t* R = sB;   // [64 rows][256]
        #pragma unroll
        for (int nt = 0; nt < 16; ++nt)
            #pragma unroll
            for (int r = 0; r < 4; ++r)
                R[(wv * 16 + quad * 4 + r) * 256 + nt * 16 + l15] = (half_t)acc[nt][r];
        __syncthreads();
        if (seg == 0) {
            // q2 hi, row-major (attn loads q2 frags straight to registers)
            for (int i = 0; i < 8; ++i) {
                int g = tid + i * 256;                 // 2048 chunks
                int row = g >> 5, cc = g & 31;
                *(half8*)(q2_hi + (size_t)(rb + row) * 256 + cc * 8) =
                    *(const half8*)(R + row * 256 + cc * 8);
            }
        } else {
            // k hi: tile-swizzled layout (tile=32 keys, 8192 elems)
            for (int i = 0; i < 8; ++i) {
                int g = tid + i * 256;
                int row = g >> 5, cc = g & 31;
                int s = row & 31;
                size_t dst = ((size_t)(rb + row) >> 5) * 8192 + s * 256 + ((cc ^ (s & 7)) * 8);
                *(half8*)(k_hi + dst) = *(const half8*)(R + row * 256 + cc * 8);
            }
        }
    } else {
        // vT repack: sV [d 256][s 64] stride 68, then tile-swizzled stores.
        // Key permutation: logical chunk q of a 32-key tile holds keys
        // {t32+4q+j}(j<4) and {t32+16+4q+(j-4)}(j>=4) -- matches the natural
        // per-lane P ownership of the attn QK^T output.
        half_t* sV = sB;
        #pragma unroll
        for (int et = 0; et < 16; ++et)
            #pragma unroll
            for (int r = 0; r < 4; ++r)
                sV[(et * 16 + quad * 4 + r) * 68 + wv * 16 + l15] = (half_t)acc[et][r];
        __syncthreads();
        const int b = rb >> 11, s0 = rb & 2047;
        for (int i = 0; i < 8; ++i) {
            int g = tid + i * 256;                 // 2048 chunks: d 256 x sc8 8
            int d = g >> 3, sc8 = g & 7;
            int kt = (s0 >> 5) + (sc8 >> 2);
            int q  = sc8 & 3;                      // logical key-chunk
            int t32 = (sc8 >> 2) * 32;
            int slot = q ^ (d & 3) ^ ((d >> 2) & 3);
            half4v a4 = *(const half4v*)(sV + d * 68 + t32 + q * 4);
            half4v b4 = *(const half4v*)(sV + d * 68 + t32 + 16 + q * 4);
            half8 hv;
            hv[0] = a4[0]; hv[1] = a4[1]; hv[2] = a4[2]; hv[3] = a4[3];
            hv[4] = b4[0]; hv[5] = b4[1]; hv[6] = b4[2]; hv[7] = b4[3];
            size_t dst = ((size_t)b * 64 + kt) * 8192 + d * 32 + slot * 8;
            *(half8*)(vT + dst) = hv;
        }
    }
}

// ---------------------------------------------------------------------------
// Kernel 3: flash attention (round-8 stable core) + FUSED k-split combine.
// After the epilogue, each block takes a device-scope ticket; the LAST of the
// KS blocks for a (b,qt) tile merges the 4 partials for its 128 rows (reads
// are L2/L3-hot). combine_kernel is deleted.
// ---------------------------------------------------------------------------
__global__ __launch_bounds__(256, 2) void attn_kernel(
    const half_t* __restrict__ q2_hi,
    const half_t* __restrict__ k_hi, const half_t* __restrict__ vT,
    half_t* __restrict__ pc, float* __restrict__ pm, float* __restrict__ pl,
    float* __restrict__ out, int* __restrict__ tickets)
{
    __shared__ __align__(16) unsigned char smem[64 * 1024];
    __shared__ int sLast;
    // K0 @0, K1 @16384, V0 @32768, V1 @49152
    float* scr = (float*)smem;              // epilogue overlay (bytes < 34816)

    const int tid  = threadIdx.x;
    const int lane = tid & 63;
    const int wv   = tid >> 6;
    const int quad = lane >> 4;
    const int l15  = lane & 15;

    const int b  = blockIdx.x & 7;          // XCD-swizzle: batch per XCD
    const int qt = (blockIdx.x >> 3) & 15;  // q-tile 0..15 (128 rows each)
    const int ks = blockIdx.x >> 7;         // k-split quarter 0..3

    const int qbase = b * 2048 + qt * 128 + wv * 32;   // wave's 32 q-rows

    // q2 B-frags resident (hi plane): B[n=qcol][k=c*32+quad*8+j]
    half8 qf[2][8];
    #pragma unroll
    for (int ct = 0; ct < 2; ++ct)
        #pragma unroll
        for (int c = 0; c < 8; ++c)
            qf[ct][c] = *(const half8*)(q2_hi +
                (size_t)(qbase + ct * 16 + l15) * 256 + c * 32 + quad * 8);

    float4_ ctx[16][2];
    #pragma unroll
    for (int dt = 0; dt < 16; ++dt) {
        ctx[dt][0] = {0.f, 0.f, 0.f, 0.f};
        ctx[dt][1] = {0.f, 0.f, 0.f, 0.f};
    }
    float m_c[2] = {-1e30f, -1e30f};
    float l_c[2] = {0.f, 0.f};              // PER-LANE partial l

    const half_t* kh_b = k_hi + (size_t)b * 64 * 8192;   // tiled layout
    const half_t* vt_b = vT   + (size_t)b * 64 * 8192;
    const int t0 = ks * NIT;

    // vt slot is dt-independent: slot = quad ^ (l15&3) ^ ((l15>>2)&3)
    const int vslot8 = (quad ^ (l15 & 3) ^ ((l15 >> 2) & 3)) * 8;

    // prologue: K(0) group then V(0) group -- FIFO order matters.
    {
        const half_t* kt_ = kh_b + (size_t)t0 * 8192;
        #pragma unroll
        for (int i = 0; i < 4; ++i) {
            const int sg = i * 4 + wv;            // 16 segments of 1 KiB each
            dma16(kt_ + sg * 512 + lane * 8, (half_t*)smem + sg * 512);
        }
        const half_t* vt_ = vt_b + (size_t)t0 * 8192;
        #pragma unroll
        for (int i = 0; i < 4; ++i) {
            const int sg = i * 4 + wv;
            dma16(vt_ + sg * 512 + lane * 8, (half_t*)(smem + 32768) + sg * 512);
        }
    }

    half8 pfp[2];   // pf from previous iteration (unused at it==0)
    #pragma unroll
    for (int ct = 0; ct < 2; ++ct)
        #pragma unroll
        for (int j = 0; j < 8; ++j) pfp[ct][j] = (half_t)0;

    for (int it = 0; it < NIT; ++it) {
        half_t* s_k  = (half_t*)(smem + ((it & 1) << 14));                // k(it)
        half_t* s_vP = (half_t*)(smem + 32768 + (((it + 1) & 1) << 14));  // vt(it-1)
        const bool pre = (it + 1 < NIT);

        // retires {V(it-1), K(it)}; leaves V(it) in flight
        asm volatile("s_waitcnt vmcnt(4)" ::: "memory");
        __builtin_amdgcn_s_barrier();        // B1
        asm volatile("" ::: "memory");

        // K(it+1) into the other k-buffer (its last reader certified at
        // B2(it-1)); cover = full iteration.
        if (pre) {
            const half_t* kt_ = kh_b + (size_t)(t0 + it + 1) * 8192;
            half_t* kdst = (half_t*)(smem + (((it + 1) & 1) << 14));
            #pragma unroll
            for (int i = 0; i < 4; ++i) {
                const int sg = i * 4 + wv;
                dma16(kt_ + sg * 512 + lane * 8, kdst + sg * 512);
            }
        }

        // ---- MERGED region: QK(it) + PV(it-1), 64 independent MFMAs.
        float4_ S[2][2];
        S[0][0] = {0.f,0.f,0.f,0.f}; S[0][1] = {0.f,0.f,0.f,0.f};
        S[1][0] = {0.f,0.f,0.f,0.f}; S[1][1] = {0.f,0.f,0.f,0.f};
        __builtin_amdgcn_s_setprio(1);
        #pragma unroll
        for (int c = 0; c < 8; ++c) {
            #pragma unroll
            for (int kt = 0; kt < 2; ++kt) {
                const int key = kt * 16 + l15;
                const int off = key * 256 + (((c * 4 + quad) ^ (key & 7)) * 8);
                half8 kf = *(const half8*)(s_k + off);
                #pragma unroll
                for (int ct = 0; ct < 2; ++ct)
                    S[kt][ct] = __builtin_amdgcn_mfma_f32_16x16x32_f16(kf, qf[ct][c], S[kt][ct], 0, 0, 0);
            }
            if (it > 0) {
                #pragma unroll
                for (int dl = 0; dl < 2; ++dl) {
                    const int dt = c * 2 + dl;
                    half8 vf = *(const half8*)(s_vP + (dt * 16 + l15) * 32 + vslot8);
                    ctx[dt][0] = __builtin_amdgcn_mfma_f32_16x16x32_f16(vf, pfp[0], ctx[dt][0], 0, 0, 0);
                    ctx[dt][1] = __builtin_amdgcn_mfma_f32_16x16x32_f16(vf, pfp[1], ctx[dt][1], 0, 0, 0);
                }
            }
        }
        __builtin_amdgcn_s_setprio(0);
        __builtin_amdgcn_sched_barrier(0);   // pin region + its lgkm waits
        __builtin_amdgcn_s_barrier();        // B2: K(it)+V(it-1) reads done
        asm volatile("" ::: "memory");

        // V(it+1) overwrites the buffer PV(it-1) just read -- safe after B2.
        if (pre) {
            const half_t* vt_ = vt_b + (size_t)(t0 + it + 1) * 8192;
            half_t* vdst = (half_t*)(smem + 32768 + (((it + 1) & 1) << 14));
            #pragma unroll
            for (int i = 0; i < 4; ++i) {
                const int sg = i * 4 + wv;
                dma16(vt_ + sg * 512 + lane * 8, vdst + sg * 512);
            }
        }

        // ---- softmax(it): shuffle-free common case.
        float mx0, mx1;   // IN-LANE max (8 scores each)
        {
            float a0 = fmaxf(fmaxf(S[0][0][0], S[0][0][1]), fmaxf(S[0][0][2], S[0][0][3]));
            float b0 = fmaxf(fmaxf(S[1][0][0], S[1][0][1]), fmaxf(S[1][0][2], S[1][0][3]));
            mx0 = fmaxf(a0, b0);
            float a1 = fmaxf(fmaxf(S[0][1][0], S[0][1][1]), fmaxf(S[0][1][2], S[0][1][3]));
            float b1 = fmaxf(fmaxf(S[1][1][0], S[1][1][1]), fmaxf(S[1][1][2], S[1][1][3]));
            mx1 = fmaxf(a1, b1);
        }
        // trigger identical to row-reduced check (__any spans all quads)
        const int doresc = __any((mx0 > m_c[0] + 8.f) || (mx1 > m_c[1] + 8.f));
        float alpha0 = 1.f, alpha1 = 1.f;
        if (doresc) {
            // rare path: full row max via cross-quad shuffles
            float r0 = fmaxf(mx0, __shfl_xor(mx0, 16));
            r0 = fmaxf(r0, __shfl_xor(r0, 32));
            float r1 = fmaxf(mx1, __shfl_xor(mx1, 16));
            r1 = fmaxf(r1, __shfl_xor(r1, 32));
            float mn0 = fmaxf(m_c[0], r0);
            float mn1 = fmaxf(m_c[1], r1);
            alpha0 = __expf(m_c[0] - mn0);
            alpha1 = __expf(m_c[1] - mn1);
            m_c[0] = mn0; m_c[1] = mn1;
        }
        // exp + per-lane l accumulation (NO shuffles)
        half8 pfc[2];
        #pragma unroll
        for (int ct = 0; ct < 2; ++ct) {
            const float mm = m_c[ct];
            float rs = 0.f;
            #pragma unroll
            for (int r = 0; r < 4; ++r) {
                float p0 = __expf(S[0][ct][r] - mm);
                float p1 = __expf(S[1][ct][r] - mm);
                rs += p0 + p1;
                pfc[ct][r]     = (half_t)p0;
                pfc[ct][4 + r] = (half_t)p1;
            }
            l_c[ct] = l_c[ct] * (ct ? alpha1 : alpha0) + rs;
        }
        // rescale AFTER PV(it-1) accumulated (data-dep on ctx regs)
        if (doresc) {
            #pragma unroll
            for (int dt = 0; dt < 16; ++dt)
                #pragma unroll
                for (int r = 0; r < 4; ++r) {
                    ctx[dt][0][r] *= alpha0;
                    ctx[dt][1][r] *= alpha1;
                }
        }
        pfp[0] = pfc[0];
        pfp[1] = pfc[1];
    }

    // drain V(NIT-1) (still in flight) + global cert; final deferred PV.
    asm volatile("s_waitcnt vmcnt(0)" ::: "memory");
    __builtin_amdgcn_s_barrier();
    asm volatile("" ::: "memory");
    {
        half_t* s_v = (half_t*)(smem + 32768 + (((NIT - 1) & 1) << 14));  // V1 @49152
        __builtin_amdgcn_s_setprio(1);
        #pragma unroll
        for (int dt = 0; dt < 16; ++dt) {
            half8 vf = *(const half8*)(s_v + (dt * 16 + l15) * 32 + vslot8);
            ctx[dt][0] = __builtin_amdgcn_mfma_f32_16x16x32_f16(vf, pfp[0], ctx[dt][0], 0, 0, 0);
            ctx[dt][1] = __builtin_amdgcn_mfma_f32_16x16x32_f16(vf, pfp[1], ctx[dt][1], 0, 0, 0);
        }
        __builtin_amdgcn_s_setprio(0);
    }

    // cross-quad l reduction (deferred from the loop; associative)
    float lt[2];
    #pragma unroll
    for (int ct = 0; ct < 2; ++ct) {
        float s = l_c[ct];
        s += __shfl_xor(s, 16);
        s += __shfl_xor(s, 32);
        lt[ct] = s;
    }

    // epilogue: normalized partial context (fp16) via per-wave LDS transpose.
    // scr regions (bytes < 34816) don't overlap V1 (@>=49152) -> safe.
    float rinv[2] = {1.0f / lt[0], 1.0f / lt[1]};
    float* sw = scr + wv * (32 * 68);       // [q 32][stride 68] f32
    half_t* pcs = pc + (size_t)ks * NROWS * 256;
    #pragma unroll
    for (int rd = 0; rd < 4; ++rd) {
        #pragma unroll
        for (int dtl = 0; dtl < 4; ++dtl) {
            const int dt = rd * 4 + dtl;
            #pragma unroll
            for (int ct = 0; ct < 2; ++ct)
                #pragma unroll
                for (int r = 0; r < 4; ++r)
                    sw[(ct * 16 + l15) * 68 + dtl * 16 + quad * 4 + r] = ctx[dt][ct][r] * rinv[ct];
        }
        #pragma unroll
        for (int i = 0; i < 8; ++i) {
            int g = lane + i * 64;
            int q = g >> 4, dc = g & 15;
            float4_ v4 = *(const float4_*)(sw + q * 68 + dc * 4);
            half4v h4;
            #pragma unroll
            for (int j = 0; j < 4; ++j) h4[j] = (half_t)v4[j];
            *(half4v*)(pcs + (size_t)(qbase + q) * 256 + rd * 64 + dc * 4) = h4;
        }
    }
    if (quad == 0) {
        #pragma unroll
        for (int ct = 0; ct < 2; ++ct) {
            const size_t row = qbase + ct * 16 + l15;
            pm[(size_t)ks * NROWS + row] = m_c[ct];
            pl[(size_t)ks * NROWS + row] = lt[ct];
        }
    }

    // ---- fused k-split combine: last block for (b,qt) merges 128 rows.
    __threadfence();                        // release own pc/pm/pl stores
    __syncthreads();                        // all waves' stores + fences done
    if (tid == 0)
        sLast = (atomicAdd(&tickets[b * 16 + qt], 1) == KS - 1);
    __syncthreads();
    if (sLast) {
        __threadfence();                    // acquire other blocks' partials
        const int rb0 = b * 2048 + qt * 128;
        const int rlb = tid >> 6;           // wave-row base
        const int c4  = (tid & 63) * 4;
        for (int i = 0; i < 32; ++i) {
            const size_t row = rb0 + rlb + i * 4;
            float mm[KS], ll[KS];
            float ms = -1e30f;
            #pragma unroll
            for (int s = 0; s < KS; ++s) {
                mm[s] = pm[(size_t)s * NROWS + row];
                ll[s] = pl[(size_t)s * NROWS + row];
                ms = fmaxf(ms, mm[s]);
            }
            float w[KS], tot = 0.f;
            #pragma unroll
            for (int s = 0; s < KS; ++s) {
                w[s] = ll[s] * __expf(mm[s] - ms);
                tot += w[s];
            }
            const float inv = 1.0f / tot;
            float4_ o = {0.f, 0.f, 0.f, 0.f};
            #pragma unroll
            for (int s = 0; s < KS; ++s) {
                half4v y = *(const half4v*)(pc + ((size_t)s * NROWS + row) * 256 + c4);
                const float wi = w[s] * inv;
                #pragma unroll
                for (int j = 0; j < 4; ++j) o[j] += wi * (float)y[j];
            }
            *(float4_*)(out + row * 256 + c4) = o;
        }
    }
}

// ---------------------------------------------------------------------------
extern "C" void kernel_launch(void* const* d_in, const int* in_sizes, int n_in,
                              void* d_out, int out_size, void* d_ws, size_t ws_size,
                              hipStream_t stream) {
    const float* x      = (const float*)d_in[0];
    const float* states = (const float*)d_in[1];
    const float* Wq     = (const float*)d_in[2];
    const float* bq     = (const float*)d_in[3];
    const float* Wk     = (const float*)d_in[4];
    const float* bk     = (const float*)d_in[5];
    const float* Wv     = (const float*)d_in[6];
    const float* bv     = (const float*)d_in[7];
    const float* Wa     = (const float*)d_in[8];
    // ba (d_in[9]) contributes a per-row constant to scores -> softmax-invariant -> unused.
    float* out = (float*)d_out;

    char* ws = (char*)d_ws;
    size_t off = 0;
    auto alloc = [&](size_t bytes) -> void* {
        void* p = ws + off;
        off += (bytes + 255) & ~(size_t)255;
        return p;
    };
    half_t* M_hi  = (half_t*)alloc(65536 * 2);
    half_t* M_lo  = (half_t*)alloc(65536 * 2);
    half_t* Wk_hi = (half_t*)alloc(65536 * 2);
    half_t* Wk_lo = (half_t*)alloc(65536 * 2);
    half_t* Wv_hi = (half_t*)alloc(65536 * 2);
    float*  bq2   = (float*)alloc(256 * 4);
    int*    tick  = (int*)alloc(512);
    half_t* q2_hi = (half_t*)alloc((size_t)NROWS * 256 * 2);
    half_t* k_hi  = (half_t*)alloc((size_t)NROWS * 256 * 2);   // tiled layout
    half_t* vT    = (half_t*)alloc((size_t)NROWS * 256 * 2);   // tiled layout
    half_t* pc    = (half_t*)alloc((size_t)KS * NROWS * 256 * 2);
    float*  pm    = (float*)alloc((size_t)KS * NROWS * 4);
    float*  pl    = (float*)alloc((size_t)KS * NROWS * 4);

    prep_kernel<<<256, 256, 0, stream>>>(Wq, Wk, Wv, Wa, bq,
                                         M_hi, M_lo, Wk_hi, Wk_lo, Wv_hi, bq2,
                                         tick);
    linear_kernel<<<768, 256, 0, stream>>>(x, states,
                                           M_hi, M_lo, bq2,
                                           Wk_hi, Wk_lo, bk,
                                           Wv_hi, bv,
                                           q2_hi, k_hi, vT);
    attn_kernel<<<8 * 16 * KS, 256, 0, stream>>>(q2_hi, k_hi, vT,
                                                 pc, pm, pl, out, tick);
}

// Round 12
// 179.231 us; speedup vs baseline: 1.4263x; 1.4263x over previous
//
#include <hip/hip_runtime.h>
#include <cstdint>
#include <cstddef>

typedef _Float16 half_t;
typedef _Float16 half8 __attribute__((ext_vector_type(8)));
typedef _Float16 half4v __attribute__((ext_vector_type(4)));
typedef float float4_ __attribute__((ext_vector_type(4)));

#define NB 8
#define SEQ 2048
#define DIM 256
#define NROWS (NB*SEQ)   // 16384
#define KS 4             // k-split -> grid 512 = 2 blocks/CU
#define NIT 16           // (2048/KS)/32 key-tiles per block

// async global->LDS DMA, 16B per lane; LDS dest = wave-uniform base + lane*16
__device__ __forceinline__ void dma16(const half_t* g, half_t* l) {
    __builtin_amdgcn_global_load_lds(
        (const __attribute__((address_space(1))) void*)g,
        (__attribute__((address_space(3))) void*)l,
        16, 0, 0);
}

// ---------------------------------------------------------------------------
// Kernel 1: fold M = Wq^T @ Wa; scores = (x M^T + bq2)·k^T (+ softmax-
// invariant const row, dropped). fp16 hi/lo planes, written PRE-SWIZZLED in
// the linear-kernel LDS image order (col m -> pos ((m>>3)^(d&7))*8 + (m&7))
// so linear can stage them with identity global_load_lds DMA.
// ---------------------------------------------------------------------------
__global__ __launch_bounds__(256) void prep_kernel(
    const float* __restrict__ Wq, const float* __restrict__ Wk,
    const float* __restrict__ Wv, const float* __restrict__ Wa,
    const float* __restrict__ bq,
    half_t* __restrict__ M_hi, half_t* __restrict__ M_lo,
    half_t* __restrict__ Wk_hi, half_t* __restrict__ Wk_lo,
    half_t* __restrict__ Wv_hi, float* __restrict__ bq2)
{
    __shared__ float sWa[256];     // Wa[:,d]
    __shared__ float sred[256];    // bq2 reduction scratch
    const int d = blockIdx.x;      // q2 out-dim (row)
    const int m = threadIdx.x;     // in-dim (col)
    sWa[m] = Wa[m * 256 + d];      // one-time column gather
    __syncthreads();

    float a0 = 0.f, a1 = 0.f, a2 = 0.f, a3 = 0.f;
    #pragma unroll 8
    for (int e = 0; e < 256; e += 4) {
        a0 += sWa[e + 0] * Wq[(e + 0) * 256 + m];
        a1 += sWa[e + 1] * Wq[(e + 1) * 256 + m];
        a2 += sWa[e + 2] * Wq[(e + 2) * 256 + m];
        a3 += sWa[e + 3] * Wq[(e + 3) * 256 + m];
    }
    float acc = (a0 + a1) + (a2 + a3);

    // swizzled position within row d (XOR involution; matches linear's reads)
    const int pos  = (((m >> 3) ^ (d & 7)) << 3) | (m & 7);
    const int sidx = d * 256 + pos;
    const int idx  = d * 256 + m;

    half_t h = (half_t)acc;
    M_hi[sidx] = h;
    M_lo[sidx] = (half_t)(acc - (float)h);
    float wk = Wk[idx];
    h = (half_t)wk;
    Wk_hi[sidx] = h;
    Wk_lo[sidx] = (half_t)(wk - (float)h);
    Wv_hi[sidx] = (half_t)Wv[idx];

    // bq2[d] = sum_e bq[e]*Wa[e,d] -- parallel tree reduction
    sred[m] = bq[m] * sWa[m];
    __syncthreads();
    #pragma unroll
    for (int s = 128; s > 0; s >>= 1) {
        if (m < s) sred[m] += sred[m + s];
        __syncthreads();
    }
    if (m == 0) bq2[d] = sred[0];
}

// ---------------------------------------------------------------------------
// Kernel 2: linears (hi/lo numerics). Weight staging via global_load_lds
// identity DMA from the pre-swizzled planes (no VALU/register round-trip).
// seg0: q2 = x@M^T+bq2, hi out, row-major. seg1: k, hi out, tile-swizzled.
// seg2: v -> vT tile-swizzled + key-permuted for reg-P PV.
// ---------------------------------------------------------------------------
__global__ __launch_bounds__(256, 2) void linear_kernel(
    const float* __restrict__ x, const float* __restrict__ states,
    const half_t* __restrict__ M_hi, const half_t* __restrict__ M_lo, const float* __restrict__ bq2,
    const half_t* __restrict__ Wk_hi, const half_t* __restrict__ Wk_lo, const float* __restrict__ bk,
    const half_t* __restrict__ Wv_hi, const float* __restrict__ bv,
    half_t* __restrict__ q2_hi,
    half_t* __restrict__ k_hi,
    half_t* __restrict__ vT)
{
    __shared__ half_t sB[2 * 64 * 256];   // weights hi+lo = 64 KiB; reused as repack buf
    half_t* sBh = sB;
    half_t* sBl = sB + 64 * 256;

    const int seg  = blockIdx.x >> 8;      // 0:q2 1:k 2:v
    const int t    = blockIdx.x & 255;
    const int tid  = threadIdx.x;
    const int lane = tid & 63;
    const int wv   = tid >> 6;
    const int quad = lane >> 4;
    const int l15  = lane & 15;
    const int rb   = t * 64;               // block row base
    const int r0   = rb + wv * 16;         // wave's 16 rows

    const float* src  = (seg == 0) ? x : states;
    const half_t* Bh  = (seg == 0) ? M_hi : (seg == 1) ? Wk_hi : Wv_hi;
    const half_t* Bl  = (seg == 0) ? M_lo : Wk_lo;
    const float* bias = (seg == 0) ? bq2 : (seg == 1) ? bk : bv;

    // A-frags direct from global: A[m=l15 -> row][k=c*32+quad*8+j], hi/lo split
    half8 ah[8], al[8];
    #pragma unroll
    for (int c = 0; c < 8; ++c) {
        const float* pa = src + (size_t)(r0 + l15) * 256 + c * 32 + quad * 8;
        float4_ u0 = *(const float4_*)pa;
        float4_ u1 = *(const float4_*)(pa + 4);
        #pragma unroll
        for (int j = 0; j < 4; ++j) {
            half_t hh = (half_t)u0[j];
            ah[c][j] = hh; al[c][j] = (half_t)(u0[j] - (float)hh);
            hh = (half_t)u1[j];
            ah[c][4 + j] = hh; al[c][4 + j] = (half_t)(u1[j] - (float)hh);
        }
    }

    float4_ acc[16];
    if (seg != 2) {
        #pragma unroll
        for (int nt = 0; nt < 16; ++nt) {
            float be = bias[nt * 16 + l15];
            acc[nt] = {be, be, be, be};
        }
    } else {
        #pragma unroll
        for (int et = 0; et < 16; ++et)
            #pragma unroll
            for (int r = 0; r < 4; ++r)
                acc[et][r] = bias[et * 16 + quad * 4 + r];
    }

    #pragma unroll
    for (int eg = 0; eg < 4; ++eg) {
        __syncthreads();   // previous e-group reads complete
        // stage weights e-group [64 e][256 k] via identity DMA (pre-swizzled)
        {
            const half_t* src_h = Bh + (size_t)eg * 16384;
            #pragma unroll
            for (int i = 0; i < 8; ++i) {
                const int sg = i * 4 + wv;            // 32 segments of 1 KiB
                dma16(src_h + sg * 512 + lane * 8, sBh + sg * 512);
            }
            if (seg != 2) {
                const half_t* src_l = Bl + (size_t)eg * 16384;
                #pragma unroll
                for (int i = 0; i < 8; ++i) {
                    const int sg = i * 4 + wv;
                    dma16(src_l + sg * 512 + lane * 8, sBl + sg * 512);
                }
            }
        }
        __syncthreads();   // vmcnt(0)+barrier: tile visible

        if (seg != 2) {
            #pragma unroll
            for (int ntl = 0; ntl < 4; ++ntl) {
                float4_ a = acc[eg * 4 + ntl];
                const int el = ntl * 16 + l15;
                #pragma unroll
                for (int c = 0; c < 8; ++c) {
                    int off = el * 256 + (((c * 4 + quad) ^ (el & 7)) * 8);
                    half8 bh = *(const half8*)(sBh + off);
                    half8 bl = *(const half8*)(sBl + off);
                    a = __builtin_amdgcn_mfma_f32_16x16x32_f16(ah[c], bh, a, 0, 0, 0);
                    a = __builtin_amdgcn_mfma_f32_16x16x32_f16(al[c], bh, a, 0, 0, 0);
                    a = __builtin_amdgcn_mfma_f32_16x16x32_f16(ah[c], bl, a, 0, 0, 0);
                }
                acc[eg * 4 + ntl] = a;
            }
        } else {
            // flipped: A = Wv tile (rows e), B = x rows -> D[e][row]
            #pragma unroll
            for (int ntl = 0; ntl < 4; ++ntl) {
                float4_ a = acc[eg * 4 + ntl];
                const int el = ntl * 16 + l15;
                #pragma unroll
                for (int c = 0; c < 8; ++c) {
                    int off = el * 256 + (((c * 4 + quad) ^ (el & 7)) * 8);
                    half8 aw = *(const half8*)(sBh + off);
                    a = __builtin_amdgcn_mfma_f32_16x16x32_f16(aw, ah[c], a, 0, 0, 0);
                }
                acc[eg * 4 + ntl] = a;
            }
        }
    }

    // epilogue: repack through LDS for coalesced half8 global stores
    __syncthreads();   // weights LDS no longer needed
    if (seg != 2) {
        half_t* R = sB;   // [64 rows][256]
        #pragma unroll
        for (int nt = 0; nt < 16; ++nt)
            #pragma unroll
            for (int r = 0; r < 4; ++r)
                R[(wv * 16 + quad * 4 + r) * 256 + nt * 16 + l15] = (half_t)acc[nt][r];
        __syncthreads();
        if (seg == 0) {
            // q2 hi, row-major (attn loads q2 frags straight to registers)
            for (int i = 0; i < 8; ++i) {
                int g = tid + i * 256;                 // 2048 chunks
                int row = g >> 5, cc = g & 31;
                *(half8*)(q2_hi + (size_t)(rb + row) * 256 + cc * 8) =
                    *(const half8*)(R + row * 256 + cc * 8);
            }
        } else {
            // k hi: tile-swizzled layout (tile=32 keys, 8192 elems)
            for (int i = 0; i < 8; ++i) {
                int g = tid + i * 256;
                int row = g >> 5, cc = g & 31;
                int s = row & 31;
                size_t dst = ((size_t)(rb + row) >> 5) * 8192 + s * 256 + ((cc ^ (s & 7)) * 8);
                *(half8*)(k_hi + dst) = *(const half8*)(R + row * 256 + cc * 8);
            }
        }
    } else {
        // vT repack: sV [d 256][s 64] stride 68, then tile-swizzled stores.
        // Key permutation: logical chunk q of a 32-key tile holds keys
        // {t32+4q+j}(j<4) and {t32+16+4q+(j-4)}(j>=4) -- matches the natural
        // per-lane P ownership of the attn QK^T output.
        half_t* sV = sB;
        #pragma unroll
        for (int et = 0; et < 16; ++et)
            #pragma unroll
            for (int r = 0; r < 4; ++r)
                sV[(et * 16 + quad * 4 + r) * 68 + wv * 16 + l15] = (half_t)acc[et][r];
        __syncthreads();
        const int b = rb >> 11, s0 = rb & 2047;
        for (int i = 0; i < 8; ++i) {
            int g = tid + i * 256;                 // 2048 chunks: d 256 x sc8 8
            int d = g >> 3, sc8 = g & 7;
            int kt = (s0 >> 5) + (sc8 >> 2);
            int q  = sc8 & 3;                      // logical key-chunk
            int t32 = (sc8 >> 2) * 32;
            int slot = q ^ (d & 3) ^ ((d >> 2) & 3);
            half4v a4 = *(const half4v*)(sV + d * 68 + t32 + q * 4);
            half4v b4 = *(const half4v*)(sV + d * 68 + t32 + 16 + q * 4);
            half8 hv;
            hv[0] = a4[0]; hv[1] = a4[1]; hv[2] = a4[2]; hv[3] = a4[3];
            hv[4] = b4[0]; hv[5] = b4[1]; hv[6] = b4[2]; hv[7] = b4[3];
            size_t dst = ((size_t)b * 64 + kt) * 8192 + d * 32 + slot * 8;
            *(half8*)(vT + dst) = hv;
        }
    }
}

// ---------------------------------------------------------------------------
// Kernel 3: flash attention (round-8/10 stable core, byte-identical).
//   - MERGED MFMA region (QK(it) + PV(it-1)), shuffle-free softmax common
//     case, per-lane l accumulation, k/vt double-buffer, 2 barriers/iter.
// Fused-combine REVERTED: the device-scope fences forced cross-XCD L2
// writeback/invalidate (+91us on attn). Kernel-boundary sync is cheaper.
// ---------------------------------------------------------------------------
__global__ __launch_bounds__(256, 2) void attn_kernel(
    const half_t* __restrict__ q2_hi,
    const half_t* __restrict__ k_hi, const half_t* __restrict__ vT,
    half_t* __restrict__ pc, float* __restrict__ pm, float* __restrict__ pl)
{
    __shared__ __align__(16) unsigned char smem[64 * 1024];
    // K0 @0, K1 @16384, V0 @32768, V1 @49152
    float* scr = (float*)smem;              // epilogue overlay (bytes < 34816)

    const int tid  = threadIdx.x;
    const int lane = tid & 63;
    const int wv   = tid >> 6;
    const int quad = lane >> 4;
    const int l15  = lane & 15;

    const int b  = blockIdx.x & 7;          // XCD-swizzle: batch per XCD
    const int qt = (blockIdx.x >> 3) & 15;  // q-tile 0..15 (128 rows each)
    const int ks = blockIdx.x >> 7;         // k-split quarter 0..3

    const int qbase = b * 2048 + qt * 128 + wv * 32;   // wave's 32 q-rows

    // q2 B-frags resident (hi plane): B[n=qcol][k=c*32+quad*8+j]
    half8 qf[2][8];
    #pragma unroll
    for (int ct = 0; ct < 2; ++ct)
        #pragma unroll
        for (int c = 0; c < 8; ++c)
            qf[ct][c] = *(const half8*)(q2_hi +
                (size_t)(qbase + ct * 16 + l15) * 256 + c * 32 + quad * 8);

    float4_ ctx[16][2];
    #pragma unroll
    for (int dt = 0; dt < 16; ++dt) {
        ctx[dt][0] = {0.f, 0.f, 0.f, 0.f};
        ctx[dt][1] = {0.f, 0.f, 0.f, 0.f};
    }
    float m_c[2] = {-1e30f, -1e30f};
    float l_c[2] = {0.f, 0.f};              // PER-LANE partial l

    const half_t* kh_b = k_hi + (size_t)b * 64 * 8192;   // tiled layout
    const half_t* vt_b = vT   + (size_t)b * 64 * 8192;
    const int t0 = ks * NIT;

    // vt slot is dt-independent: slot = quad ^ (l15&3) ^ ((l15>>2)&3)
    const int vslot8 = (quad ^ (l15 & 3) ^ ((l15 >> 2) & 3)) * 8;

    // prologue: K(0) group then V(0) group -- FIFO order matters.
    {
        const half_t* kt_ = kh_b + (size_t)t0 * 8192;
        #pragma unroll
        for (int i = 0; i < 4; ++i) {
            const int sg = i * 4 + wv;            // 16 segments of 1 KiB each
            dma16(kt_ + sg * 512 + lane * 8, (half_t*)smem + sg * 512);
        }
        const half_t* vt_ = vt_b + (size_t)t0 * 8192;
        #pragma unroll
        for (int i = 0; i < 4; ++i) {
            const int sg = i * 4 + wv;
            dma16(vt_ + sg * 512 + lane * 8, (half_t*)(smem + 32768) + sg * 512);
        }
    }

    half8 pfp[2];   // pf from previous iteration (unused at it==0)
    #pragma unroll
    for (int ct = 0; ct < 2; ++ct)
        #pragma unroll
        for (int j = 0; j < 8; ++j) pfp[ct][j] = (half_t)0;

    for (int it = 0; it < NIT; ++it) {
        half_t* s_k  = (half_t*)(smem + ((it & 1) << 14));                // k(it)
        half_t* s_vP = (half_t*)(smem + 32768 + (((it + 1) & 1) << 14));  // vt(it-1)
        const bool pre = (it + 1 < NIT);

        // retires {V(it-1), K(it)}; leaves V(it) in flight
        asm volatile("s_waitcnt vmcnt(4)" ::: "memory");
        __builtin_amdgcn_s_barrier();        // B1
        asm volatile("" ::: "memory");

        // K(it+1) into the other k-buffer (its last reader certified at
        // B2(it-1)); cover = full iteration.
        if (pre) {
            const half_t* kt_ = kh_b + (size_t)(t0 + it + 1) * 8192;
            half_t* kdst = (half_t*)(smem + (((it + 1) & 1) << 14));
            #pragma unroll
            for (int i = 0; i < 4; ++i) {
                const int sg = i * 4 + wv;
                dma16(kt_ + sg * 512 + lane * 8, kdst + sg * 512);
            }
        }

        // ---- MERGED region: QK(it) + PV(it-1), 64 independent MFMAs.
        float4_ S[2][2];
        S[0][0] = {0.f,0.f,0.f,0.f}; S[0][1] = {0.f,0.f,0.f,0.f};
        S[1][0] = {0.f,0.f,0.f,0.f}; S[1][1] = {0.f,0.f,0.f,0.f};
        __builtin_amdgcn_s_setprio(1);
        #pragma unroll
        for (int c = 0; c < 8; ++c) {
            #pragma unroll
            for (int kt = 0; kt < 2; ++kt) {
                const int key = kt * 16 + l15;
                const int off = key * 256 + (((c * 4 + quad) ^ (key & 7)) * 8);
                half8 kf = *(const half8*)(s_k + off);
                #pragma unroll
                for (int ct = 0; ct < 2; ++ct)
                    S[kt][ct] = __builtin_amdgcn_mfma_f32_16x16x32_f16(kf, qf[ct][c], S[kt][ct], 0, 0, 0);
            }
            if (it > 0) {
                #pragma unroll
                for (int dl = 0; dl < 2; ++dl) {
                    const int dt = c * 2 + dl;
                    half8 vf = *(const half8*)(s_vP + (dt * 16 + l15) * 32 + vslot8);
                    ctx[dt][0] = __builtin_amdgcn_mfma_f32_16x16x32_f16(vf, pfp[0], ctx[dt][0], 0, 0, 0);
                    ctx[dt][1] = __builtin_amdgcn_mfma_f32_16x16x32_f16(vf, pfp[1], ctx[dt][1], 0, 0, 0);
                }
            }
        }
        __builtin_amdgcn_s_setprio(0);
        __builtin_amdgcn_sched_barrier(0);   // pin region + its lgkm waits
        __builtin_amdgcn_s_barrier();        // B2: K(it)+V(it-1) reads done
        asm volatile("" ::: "memory");

        // V(it+1) overwrites the buffer PV(it-1) just read -- safe after B2.
        if (pre) {
            const half_t* vt_ = vt_b + (size_t)(t0 + it + 1) * 8192;
            half_t* vdst = (half_t*)(smem + 32768 + (((it + 1) & 1) << 14));
            #pragma unroll
            for (int i = 0; i < 4; ++i) {
                const int sg = i * 4 + wv;
                dma16(vt_ + sg * 512 + lane * 8, vdst + sg * 512);
            }
        }

        // ---- softmax(it): shuffle-free common case.
        float mx0, mx1;   // IN-LANE max (8 scores each)
        {
            float a0 = fmaxf(fmaxf(S[0][0][0], S[0][0][1]), fmaxf(S[0][0][2], S[0][0][3]));
            float b0 = fmaxf(fmaxf(S[1][0][0], S[1][0][1]), fmaxf(S[1][0][2], S[1][0][3]));
            mx0 = fmaxf(a0, b0);
            float a1 = fmaxf(fmaxf(S[0][1][0], S[0][1][1]), fmaxf(S[0][1][2], S[0][1][3]));
            float b1 = fmaxf(fmaxf(S[1][1][0], S[1][1][1]), fmaxf(S[1][1][2], S[1][1][3]));
            mx1 = fmaxf(a1, b1);
        }
        // trigger identical to row-reduced check (__any spans all quads)
        const int doresc = __any((mx0 > m_c[0] + 8.f) || (mx1 > m_c[1] + 8.f));
        float alpha0 = 1.f, alpha1 = 1.f;
        if (doresc) {
            // rare path: full row max via cross-quad shuffles
            float r0 = fmaxf(mx0, __shfl_xor(mx0, 16));
            r0 = fmaxf(r0, __shfl_xor(r0, 32));
            float r1 = fmaxf(mx1, __shfl_xor(mx1, 16));
            r1 = fmaxf(r1, __shfl_xor(r1, 32));
            float mn0 = fmaxf(m_c[0], r0);
            float mn1 = fmaxf(m_c[1], r1);
            alpha0 = __expf(m_c[0] - mn0);
            alpha1 = __expf(m_c[1] - mn1);
            m_c[0] = mn0; m_c[1] = mn1;
        }
        // exp + per-lane l accumulation (NO shuffles)
        half8 pfc[2];
        #pragma unroll
        for (int ct = 0; ct < 2; ++ct) {
            const float mm = m_c[ct];
            float rs = 0.f;
            #pragma unroll
            for (int r = 0; r < 4; ++r) {
                float p0 = __expf(S[0][ct][r] - mm);
                float p1 = __expf(S[1][ct][r] - mm);
                rs += p0 + p1;
                pfc[ct][r]     = (half_t)p0;
                pfc[ct][4 + r] = (half_t)p1;
            }
            l_c[ct] = l_c[ct] * (ct ? alpha1 : alpha0) + rs;
        }
        // rescale AFTER PV(it-1) accumulated (data-dep on ctx regs)
        if (doresc) {
            #pragma unroll
            for (int dt = 0; dt < 16; ++dt)
                #pragma unroll
                for (int r = 0; r < 4; ++r) {
                    ctx[dt][0][r] *= alpha0;
                    ctx[dt][1][r] *= alpha1;
                }
        }
        pfp[0] = pfc[0];
        pfp[1] = pfc[1];
    }

    // drain V(NIT-1) (still in flight) + global cert; final deferred PV.
    asm volatile("s_waitcnt vmcnt(0)" ::: "memory");
    __builtin_amdgcn_s_barrier();
    asm volatile("" ::: "memory");
    {
        half_t* s_v = (half_t*)(smem + 32768 + (((NIT - 1) & 1) << 14));  // V1 @49152
        __builtin_amdgcn_s_setprio(1);
        #pragma unroll
        for (int dt = 0; dt < 16; ++dt) {
            half8 vf = *(const half8*)(s_v + (dt * 16 + l15) * 32 + vslot8);
            ctx[dt][0] = __builtin_amdgcn_mfma_f32_16x16x32_f16(vf, pfp[0], ctx[dt][0], 0, 0, 0);
            ctx[dt][1] = __builtin_amdgcn_mfma_f32_16x16x32_f16(vf, pfp[1], ctx[dt][1], 0, 0, 0);
        }
        __builtin_amdgcn_s_setprio(0);
    }

    // cross-quad l reduction (deferred from the loop; associative)
    float lt[2];
    #pragma unroll
    for (int ct = 0; ct < 2; ++ct) {
        float s = l_c[ct];
        s += __shfl_xor(s, 16);
        s += __shfl_xor(s, 32);
        lt[ct] = s;
    }

    // epilogue: normalized partial context (fp16) via per-wave LDS transpose.
    // scr regions (bytes < 34816) don't overlap V1 (@>=49152) -> safe.
    float rinv[2] = {1.0f / lt[0], 1.0f / lt[1]};
    float* sw = scr + wv * (32 * 68);       // [q 32][stride 68] f32
    half_t* pcs = pc + (size_t)ks * NROWS * 256;
    #pragma unroll
    for (int rd = 0; rd < 4; ++rd) {
        #pragma unroll
        for (int dtl = 0; dtl < 4; ++dtl) {
            const int dt = rd * 4 + dtl;
            #pragma unroll
            for (int ct = 0; ct < 2; ++ct)
                #pragma unroll
                for (int r = 0; r < 4; ++r)
                    sw[(ct * 16 + l15) * 68 + dtl * 16 + quad * 4 + r] = ctx[dt][ct][r] * rinv[ct];
        }
        #pragma unroll
        for (int i = 0; i < 8; ++i) {
            int g = lane + i * 64;
            int q = g >> 4, dc = g & 15;
            float4_ v4 = *(const float4_*)(sw + q * 68 + dc * 4);
            half4v h4;
            #pragma unroll
            for (int j = 0; j < 4; ++j) h4[j] = (half_t)v4[j];
            *(half4v*)(pcs + (size_t)(qbase + q) * 256 + rd * 64 + dc * 4) = h4;
        }
    }
    if (quad == 0) {
        #pragma unroll
        for (int ct = 0; ct < 2; ++ct) {
            const size_t row = qbase + ct * 16 + l15;
            pm[(size_t)ks * NROWS + row] = m_c[ct];
            pl[(size_t)ks * NROWS + row] = lt[ct];
        }
    }
}

// ---------------------------------------------------------------------------
// Kernel 4: merge the KS k-split partials.
// ---------------------------------------------------------------------------
__global__ __launch_bounds__(256) void combine_kernel(
    const half_t* __restrict__ pc, const float* __restrict__ pm,
    const float* __restrict__ pl, float* __restrict__ out)
{
    const int t = threadIdx.x;
    const int row = blockIdx.x * 4 + (t >> 6);
    const int d0 = (t & 63) * 4;
    float m[KS], l[KS];
    float ms = -1e30f;
    #pragma unroll
    for (int i = 0; i < KS; ++i) {
        m[i] = pm[(size_t)i * NROWS + row];
        l[i] = pl[(size_t)i * NROWS + row];
        ms = fmaxf(ms, m[i]);
    }
    float w[KS], tot = 0.f;
    #pragma unroll
    for (int i = 0; i < KS; ++i) {
        w[i] = l[i] * __expf(m[i] - ms);
        tot += w[i];
    }
    float inv = 1.0f / tot;
    float4_ o = {0.f, 0.f, 0.f, 0.f};
    #pragma unroll
    for (int i = 0; i < KS; ++i) {
        half4v y = *(const half4v*)(pc + ((size_t)i * NROWS + row) * 256 + d0);
        float wi = w[i] * inv;
        #pragma unroll
        for (int j = 0; j < 4; ++j) o[j] += wi * (float)y[j];
    }
    *(float4_*)(out + (size_t)row * 256 + d0) = o;
}

// ---------------------------------------------------------------------------
extern "C" void kernel_launch(void* const* d_in, const int* in_sizes, int n_in,
                              void* d_out, int out_size, void* d_ws, size_t ws_size,
                              hipStream_t stream) {
    const float* x      = (const float*)d_in[0];
    const float* states = (const float*)d_in[1];
    const float* Wq     = (const float*)d_in[2];
    const float* bq     = (const float*)d_in[3];
    const float* Wk     = (const float*)d_in[4];
    const float* bk     = (const float*)d_in[5];
    const float* Wv     = (const float*)d_in[6];
    const float* bv     = (const float*)d_in[7];
    const float* Wa     = (const float*)d_in[8];
    // ba (d_in[9]) contributes a per-row constant to scores -> softmax-invariant -> unused.
    float* out = (float*)d_out;

    char* ws = (char*)d_ws;
    size_t off = 0;
    auto alloc = [&](size_t bytes) -> void* {
        void* p = ws + off;
        off += (bytes + 255) & ~(size_t)255;
        return p;
    };
    half_t* M_hi  = (half_t*)alloc(65536 * 2);
    half_t* M_lo  = (half_t*)alloc(65536 * 2);
    half_t* Wk_hi = (half_t*)alloc(65536 * 2);
    half_t* Wk_lo = (half_t*)alloc(65536 * 2);
    half_t* Wv_hi = (half_t*)alloc(65536 * 2);
    float*  bq2   = (float*)alloc(256 * 4);
    half_t* q2_hi = (half_t*)alloc((size_t)NROWS * 256 * 2);
    half_t* k_hi  = (half_t*)alloc((size_t)NROWS * 256 * 2);   // tiled layout
    half_t* vT    = (half_t*)alloc((size_t)NROWS * 256 * 2);   // tiled layout
    half_t* pc    = (half_t*)alloc((size_t)KS * NROWS * 256 * 2);
    float*  pm    = (float*)alloc((size_t)KS * NROWS * 4);
    float*  pl    = (float*)alloc((size_t)KS * NROWS * 4);

    prep_kernel<<<256, 256, 0, stream>>>(Wq, Wk, Wv, Wa, bq,
                                         M_hi, M_lo, Wk_hi, Wk_lo, Wv_hi, bq2);
    linear_kernel<<<768, 256, 0, stream>>>(x, states,
                                           M_hi, M_lo, bq2,
                                           Wk_hi, Wk_lo, bk,
                                           Wv_hi, bv,
                                           q2_hi, k_hi, vT);
    attn_kernel<<<8 * 16 * KS, 256, 0, stream>>>(q2_hi, k_hi, vT,
                                                 pc, pm, pl);
    combine_kernel<<<NROWS / 4, 256, 0, stream>>>(pc, pm, pl, out);
}

// Round 13
// 176.966 us; speedup vs baseline: 1.4445x; 1.0128x over previous
//
#include <hip/hip_runtime.h>
#include <cstdint>
#include <cstddef>

typedef _Float16 half_t;
typedef _Float16 half8 __attribute__((ext_vector_type(8)));
typedef _Float16 half4v __attribute__((ext_vector_type(4)));
typedef float float4_ __attribute__((ext_vector_type(4)));

#define NB 8
#define SEQ 2048
#define DIM 256
#define NROWS (NB*SEQ)   // 16384
#define KS 4             // k-split -> grid 512 = 2 blocks/CU
#define NIT 16           // (2048/KS)/32 key-tiles per block

// async global->LDS DMA, 16B per lane; LDS dest = wave-uniform base + lane*16
__device__ __forceinline__ void dma16(const half_t* g, half_t* l) {
    __builtin_amdgcn_global_load_lds(
        (const __attribute__((address_space(1))) void*)g,
        (__attribute__((address_space(3))) void*)l,
        16, 0, 0);
}

// ---------------------------------------------------------------------------
// Kernel 1: fold M = Wq^T @ Wa; scores = (x M^T + bq2)·k^T (+ softmax-
// invariant const row, dropped). fp16 hi/lo planes, written PRE-SWIZZLED in
// the linear-kernel LDS image order (col m -> pos ((m>>3)^(d&7))*8 + (m&7))
// so linear can stage them with identity global_load_lds DMA.
// ---------------------------------------------------------------------------
__global__ __launch_bounds__(256) void prep_kernel(
    const float* __restrict__ Wq, const float* __restrict__ Wk,
    const float* __restrict__ Wv, const float* __restrict__ Wa,
    const float* __restrict__ bq,
    half_t* __restrict__ M_hi, half_t* __restrict__ M_lo,
    half_t* __restrict__ Wk_hi, half_t* __restrict__ Wk_lo,
    half_t* __restrict__ Wv_hi, float* __restrict__ bq2)
{
    __shared__ float sWa[256];     // Wa[:,d]
    __shared__ float sred[256];    // bq2 reduction scratch
    const int d = blockIdx.x;      // q2 out-dim (row)
    const int m = threadIdx.x;     // in-dim (col)
    sWa[m] = Wa[m * 256 + d];      // one-time column gather
    __syncthreads();

    float a0 = 0.f, a1 = 0.f, a2 = 0.f, a3 = 0.f;
    #pragma unroll 8
    for (int e = 0; e < 256; e += 4) {
        a0 += sWa[e + 0] * Wq[(e + 0) * 256 + m];
        a1 += sWa[e + 1] * Wq[(e + 1) * 256 + m];
        a2 += sWa[e + 2] * Wq[(e + 2) * 256 + m];
        a3 += sWa[e + 3] * Wq[(e + 3) * 256 + m];
    }
    float acc = (a0 + a1) + (a2 + a3);

    // swizzled position within row d (XOR involution; matches linear's reads)
    const int pos  = (((m >> 3) ^ (d & 7)) << 3) | (m & 7);
    const int sidx = d * 256 + pos;
    const int idx  = d * 256 + m;

    half_t h = (half_t)acc;
    M_hi[sidx] = h;
    M_lo[sidx] = (half_t)(acc - (float)h);
    float wk = Wk[idx];
    h = (half_t)wk;
    Wk_hi[sidx] = h;
    Wk_lo[sidx] = (half_t)(wk - (float)h);
    Wv_hi[sidx] = (half_t)Wv[idx];

    // bq2[d] = sum_e bq[e]*Wa[e,d] -- parallel tree reduction
    sred[m] = bq[m] * sWa[m];
    __syncthreads();
    #pragma unroll
    for (int s = 128; s > 0; s >>= 1) {
        if (m < s) sred[m] += sred[m + s];
        __syncthreads();
    }
    if (m == 0) bq2[d] = sred[0];
}

// ---------------------------------------------------------------------------
// Kernel 2: linears (hi/lo numerics), PIPELINED weight staging: 8 half-groups
// of 32 out-dims, double-buffered (2x32KB LDS), one barrier per half-group,
// stage(h+1) issued right after the residency barrier so its DMA flight is
// covered by MFMA(h). Replaces 4 uncovered full-drain syncs (round-0 stall
// class) with 8 covered waits.
// seg0: q2 = x@M^T+bq2, hi out, row-major. seg1: k, hi out, tile-swizzled.
// seg2: v -> vT tile-swizzled + key-permuted for reg-P PV.
// ---------------------------------------------------------------------------
__global__ __launch_bounds__(256, 2) void linear_kernel(
    const float* __restrict__ x, const float* __restrict__ states,
    const half_t* __restrict__ M_hi, const half_t* __restrict__ M_lo, const float* __restrict__ bq2,
    const half_t* __restrict__ Wk_hi, const half_t* __restrict__ Wk_lo, const float* __restrict__ bk,
    const half_t* __restrict__ Wv_hi, const float* __restrict__ bv,
    half_t* __restrict__ q2_hi,
    half_t* __restrict__ k_hi,
    half_t* __restrict__ vT)
{
    __shared__ half_t sB[2 * 64 * 256];   // 64 KiB: 2 bufs x [hi 16KB][lo 16KB]; reused as repack

    const int seg  = blockIdx.x >> 8;      // 0:q2 1:k 2:v
    const int t    = blockIdx.x & 255;
    const int tid  = threadIdx.x;
    const int lane = tid & 63;
    const int wv   = tid >> 6;
    const int quad = lane >> 4;
    const int l15  = lane & 15;
    const int rb   = t * 64;               // block row base
    const int r0   = rb + wv * 16;         // wave's 16 rows

    const float* src  = (seg == 0) ? x : states;
    const half_t* Bh  = (seg == 0) ? M_hi : (seg == 1) ? Wk_hi : Wv_hi;
    const half_t* Bl  = (seg == 0) ? M_lo : Wk_lo;
    const float* bias = (seg == 0) ? bq2 : (seg == 1) ? bk : bv;

    const int hgsz = (seg != 2) ? 16384 : 8192;   // halfs per buffer (hi[+lo])

    // A-frags direct from global: A[m=l15 -> row][k=c*32+quad*8+j], hi/lo split
    half8 ah[8], al[8];
    #pragma unroll
    for (int c = 0; c < 8; ++c) {
        const float* pa = src + (size_t)(r0 + l15) * 256 + c * 32 + quad * 8;
        float4_ u0 = *(const float4_*)pa;
        float4_ u1 = *(const float4_*)(pa + 4);
        #pragma unroll
        for (int j = 0; j < 4; ++j) {
            half_t hh = (half_t)u0[j];
            ah[c][j] = hh; al[c][j] = (half_t)(u0[j] - (float)hh);
            hh = (half_t)u1[j];
            ah[c][4 + j] = hh; al[c][4 + j] = (half_t)(u1[j] - (float)hh);
        }
    }

    float4_ acc[16];
    if (seg != 2) {
        #pragma unroll
        for (int nt = 0; nt < 16; ++nt) {
            float be = bias[nt * 16 + l15];
            acc[nt] = {be, be, be, be};
        }
    } else {
        #pragma unroll
        for (int et = 0; et < 16; ++et)
            #pragma unroll
            for (int r = 0; r < 4; ++r)
                acc[et][r] = bias[et * 16 + quad * 4 + r];
    }

    // stage half-group h (32 out-dims: 16KB hi [+16KB lo]) into dst buffer
    auto stage = [&](int h, half_t* dst) {
        const half_t* src_h = Bh + (size_t)h * 8192;
        #pragma unroll
        for (int i = 0; i < 4; ++i) {
            const int sg = i * 4 + wv;            // 16 segments of 1 KiB
            dma16(src_h + sg * 512 + lane * 8, dst + sg * 512);
        }
        if (seg != 2) {
            const half_t* src_l = Bl + (size_t)h * 8192;
            #pragma unroll
            for (int i = 0; i < 4; ++i) {
                const int sg = i * 4 + wv;
                dma16(src_l + sg * 512 + lane * 8, dst + 8192 + sg * 512);
            }
        }
    };

    stage(0, sB);
    for (int h = 0; h < 8; ++h) {
        // only stage(h) outstanding; its flight was covered by MFMA(h-1)
        asm volatile("s_waitcnt vmcnt(0)" ::: "memory");
        __builtin_amdgcn_s_barrier();      // buf[h&1] resident; MFMA(h-1) done
        asm volatile("" ::: "memory");
        if (h < 7) stage(h + 1, sB + ((h + 1) & 1) * hgsz);

        half_t* bufh = sB + (h & 1) * hgsz;
        if (seg != 2) {
            #pragma unroll
            for (int ntl = 0; ntl < 2; ++ntl) {
                float4_ a = acc[h * 2 + ntl];
                const int el = ntl * 16 + l15;     // local row 0..31; el&7 == global&7
                #pragma unroll
                for (int c = 0; c < 8; ++c) {
                    int off = el * 256 + (((c * 4 + quad) ^ (el & 7)) * 8);
                    half8 bh = *(const half8*)(bufh + off);
                    half8 bl = *(const half8*)(bufh + 8192 + off);
                    a = __builtin_amdgcn_mfma_f32_16x16x32_f16(ah[c], bh, a, 0, 0, 0);
                    a = __builtin_amdgcn_mfma_f32_16x16x32_f16(al[c], bh, a, 0, 0, 0);
                    a = __builtin_amdgcn_mfma_f32_16x16x32_f16(ah[c], bl, a, 0, 0, 0);
                }
                acc[h * 2 + ntl] = a;
            }
        } else {
            // flipped: A = Wv tile (rows e), B = x rows -> D[e][row]
            #pragma unroll
            for (int ntl = 0; ntl < 2; ++ntl) {
                float4_ a = acc[h * 2 + ntl];
                const int el = ntl * 16 + l15;
                #pragma unroll
                for (int c = 0; c < 8; ++c) {
                    int off = el * 256 + (((c * 4 + quad) ^ (el & 7)) * 8);
                    half8 aw = *(const half8*)(bufh + off);
                    a = __builtin_amdgcn_mfma_f32_16x16x32_f16(aw, ah[c], a, 0, 0, 0);
                }
                acc[h * 2 + ntl] = a;
            }
        }
        __builtin_amdgcn_sched_barrier(0);   // pin MFMA(h) + lgkm waits above next fence
    }

    // epilogue: repack through LDS for coalesced half8 global stores
    __syncthreads();   // all waves past MFMA(7); weights LDS free
    if (seg != 2) {
        half_t* R = sB;   // [64 rows][256]
        #pragma unroll
        for (int nt = 0; nt < 16; ++nt)
            #pragma unroll
            for (int r = 0; r < 4; ++r)
                R[(wv * 16 + quad * 4 + r) * 256 + nt * 16 + l15] = (half_t)acc[nt][r];
        __syncthreads();
        if (seg == 0) {
            // q2 hi, row-major (attn loads q2 frags straight to registers)
            for (int i = 0; i < 8; ++i) {
                int g = tid + i * 256;                 // 2048 chunks
                int row = g >> 5, cc = g & 31;
                *(half8*)(q2_hi + (size_t)(rb + row) * 256 + cc * 8) =
                    *(const half8*)(R + row * 256 + cc * 8);
            }
        } else {
            // k hi: tile-swizzled layout (tile=32 keys, 8192 elems)
            for (int i = 0; i < 8; ++i) {
                int g = tid + i * 256;
                int row = g >> 5, cc = g & 31;
                int s = row & 31;
                size_t dst = ((size_t)(rb + row) >> 5) * 8192 + s * 256 + ((cc ^ (s & 7)) * 8);
                *(half8*)(k_hi + dst) = *(const half8*)(R + row * 256 + cc * 8);
            }
        }
    } else {
        // vT repack: sV [d 256][s 64] stride 68, then tile-swizzled stores.
        // Key permutation: logical chunk q of a 32-key tile holds keys
        // {t32+4q+j}(j<4) and {t32+16+4q+(j-4)}(j>=4) -- matches the natural
        // per-lane P ownership of the attn QK^T output.
        half_t* sV = sB;
        #pragma unroll
        for (int et = 0; et < 16; ++et)
            #pragma unroll
            for (int r = 0; r < 4; ++r)
                sV[(et * 16 + quad * 4 + r) * 68 + wv * 16 + l15] = (half_t)acc[et][r];
        __syncthreads();
        const int b = rb >> 11, s0 = rb & 2047;
        for (int i = 0; i < 8; ++i) {
            int g = tid + i * 256;                 // 2048 chunks: d 256 x sc8 8
            int d = g >> 3, sc8 = g & 7;
            int kt = (s0 >> 5) + (sc8 >> 2);
            int q  = sc8 & 3;                      // logical key-chunk
            int t32 = (sc8 >> 2) * 32;
            int slot = q ^ (d & 3) ^ ((d >> 2) & 3);
            half4v a4 = *(const half4v*)(sV + d * 68 + t32 + q * 4);
            half4v b4 = *(const half4v*)(sV + d * 68 + t32 + 16 + q * 4);
            half8 hv;
            hv[0] = a4[0]; hv[1] = a4[1]; hv[2] = a4[2]; hv[3] = a4[3];
            hv[4] = b4[0]; hv[5] = b4[1]; hv[6] = b4[2]; hv[7] = b4[3];
            size_t dst = ((size_t)b * 64 + kt) * 8192 + d * 32 + slot * 8;
            *(half8*)(vT + dst) = hv;
        }
    }
}

// ---------------------------------------------------------------------------
// Kernel 3: flash attention (round-8/10 stable core, byte-identical).
//   - MERGED MFMA region (QK(it) + PV(it-1)), shuffle-free softmax common
//     case, per-lane l accumulation, k/vt double-buffer, 2 barriers/iter.
// ---------------------------------------------------------------------------
__global__ __launch_bounds__(256, 2) void attn_kernel(
    const half_t* __restrict__ q2_hi,
    const half_t* __restrict__ k_hi, const half_t* __restrict__ vT,
    half_t* __restrict__ pc, float* __restrict__ pm, float* __restrict__ pl)
{
    __shared__ __align__(16) unsigned char smem[64 * 1024];
    // K0 @0, K1 @16384, V0 @32768, V1 @49152
    float* scr = (float*)smem;              // epilogue overlay (bytes < 34816)

    const int tid  = threadIdx.x;
    const int lane = tid & 63;
    const int wv   = tid >> 6;
    const int quad = lane >> 4;
    const int l15  = lane & 15;

    const int b  = blockIdx.x & 7;          // XCD-swizzle: batch per XCD
    const int qt = (blockIdx.x >> 3) & 15;  // q-tile 0..15 (128 rows each)
    const int ks = blockIdx.x >> 7;         // k-split quarter 0..3

    const int qbase = b * 2048 + qt * 128 + wv * 32;   // wave's 32 q-rows

    // q2 B-frags resident (hi plane): B[n=qcol][k=c*32+quad*8+j]
    half8 qf[2][8];
    #pragma unroll
    for (int ct = 0; ct < 2; ++ct)
        #pragma unroll
        for (int c = 0; c < 8; ++c)
            qf[ct][c] = *(const half8*)(q2_hi +
                (size_t)(qbase + ct * 16 + l15) * 256 + c * 32 + quad * 8);

    float4_ ctx[16][2];
    #pragma unroll
    for (int dt = 0; dt < 16; ++dt) {
        ctx[dt][0] = {0.f, 0.f, 0.f, 0.f};
        ctx[dt][1] = {0.f, 0.f, 0.f, 0.f};
    }
    float m_c[2] = {-1e30f, -1e30f};
    float l_c[2] = {0.f, 0.f};              // PER-LANE partial l

    const half_t* kh_b = k_hi + (size_t)b * 64 * 8192;   // tiled layout
    const half_t* vt_b = vT   + (size_t)b * 64 * 8192;
    const int t0 = ks * NIT;

    // vt slot is dt-independent: slot = quad ^ (l15&3) ^ ((l15>>2)&3)
    const int vslot8 = (quad ^ (l15 & 3) ^ ((l15 >> 2) & 3)) * 8;

    // prologue: K(0) group then V(0) group -- FIFO order matters.
    {
        const half_t* kt_ = kh_b + (size_t)t0 * 8192;
        #pragma unroll
        for (int i = 0; i < 4; ++i) {
            const int sg = i * 4 + wv;            // 16 segments of 1 KiB each
            dma16(kt_ + sg * 512 + lane * 8, (half_t*)smem + sg * 512);
        }
        const half_t* vt_ = vt_b + (size_t)t0 * 8192;
        #pragma unroll
        for (int i = 0; i < 4; ++i) {
            const int sg = i * 4 + wv;
            dma16(vt_ + sg * 512 + lane * 8, (half_t*)(smem + 32768) + sg * 512);
        }
    }

    half8 pfp[2];   // pf from previous iteration (unused at it==0)
    #pragma unroll
    for (int ct = 0; ct < 2; ++ct)
        #pragma unroll
        for (int j = 0; j < 8; ++j) pfp[ct][j] = (half_t)0;

    for (int it = 0; it < NIT; ++it) {
        half_t* s_k  = (half_t*)(smem + ((it & 1) << 14));                // k(it)
        half_t* s_vP = (half_t*)(smem + 32768 + (((it + 1) & 1) << 14));  // vt(it-1)
        const bool pre = (it + 1 < NIT);

        // retires {V(it-1), K(it)}; leaves V(it) in flight
        asm volatile("s_waitcnt vmcnt(4)" ::: "memory");
        __builtin_amdgcn_s_barrier();        // B1
        asm volatile("" ::: "memory");

        // K(it+1) into the other k-buffer (its last reader certified at
        // B2(it-1)); cover = full iteration.
        if (pre) {
            const half_t* kt_ = kh_b + (size_t)(t0 + it + 1) * 8192;
            half_t* kdst = (half_t*)(smem + (((it + 1) & 1) << 14));
            #pragma unroll
            for (int i = 0; i < 4; ++i) {
                const int sg = i * 4 + wv;
                dma16(kt_ + sg * 512 + lane * 8, kdst + sg * 512);
            }
        }

        // ---- MERGED region: QK(it) + PV(it-1), 64 independent MFMAs.
        float4_ S[2][2];
        S[0][0] = {0.f,0.f,0.f,0.f}; S[0][1] = {0.f,0.f,0.f,0.f};
        S[1][0] = {0.f,0.f,0.f,0.f}; S[1][1] = {0.f,0.f,0.f,0.f};
        __builtin_amdgcn_s_setprio(1);
        #pragma unroll
        for (int c = 0; c < 8; ++c) {
            #pragma unroll
            for (int kt = 0; kt < 2; ++kt) {
                const int key = kt * 16 + l15;
                const int off = key * 256 + (((c * 4 + quad) ^ (key & 7)) * 8);
                half8 kf = *(const half8*)(s_k + off);
                #pragma unroll
                for (int ct = 0; ct < 2; ++ct)
                    S[kt][ct] = __builtin_amdgcn_mfma_f32_16x16x32_f16(kf, qf[ct][c], S[kt][ct], 0, 0, 0);
            }
            if (it > 0) {
                #pragma unroll
                for (int dl = 0; dl < 2; ++dl) {
                    const int dt = c * 2 + dl;
                    half8 vf = *(const half8*)(s_vP + (dt * 16 + l15) * 32 + vslot8);
                    ctx[dt][0] = __builtin_amdgcn_mfma_f32_16x16x32_f16(vf, pfp[0], ctx[dt][0], 0, 0, 0);
                    ctx[dt][1] = __builtin_amdgcn_mfma_f32_16x16x32_f16(vf, pfp[1], ctx[dt][1], 0, 0, 0);
                }
            }
        }
        __builtin_amdgcn_s_setprio(0);
        __builtin_amdgcn_sched_barrier(0);   // pin region + its lgkm waits
        __builtin_amdgcn_s_barrier();        // B2: K(it)+V(it-1) reads done
        asm volatile("" ::: "memory");

        // V(it+1) overwrites the buffer PV(it-1) just read -- safe after B2.
        if (pre) {
            const half_t* vt_ = vt_b + (size_t)(t0 + it + 1) * 8192;
            half_t* vdst = (half_t*)(smem + 32768 + (((it + 1) & 1) << 14));
            #pragma unroll
            for (int i = 0; i < 4; ++i) {
                const int sg = i * 4 + wv;
                dma16(vt_ + sg * 512 + lane * 8, vdst + sg * 512);
            }
        }

        // ---- softmax(it): shuffle-free common case.
        float mx0, mx1;   // IN-LANE max (8 scores each)
        {
            float a0 = fmaxf(fmaxf(S[0][0][0], S[0][0][1]), fmaxf(S[0][0][2], S[0][0][3]));
            float b0 = fmaxf(fmaxf(S[1][0][0], S[1][0][1]), fmaxf(S[1][0][2], S[1][0][3]));
            mx0 = fmaxf(a0, b0);
            float a1 = fmaxf(fmaxf(S[0][1][0], S[0][1][1]), fmaxf(S[0][1][2], S[0][1][3]));
            float b1 = fmaxf(fmaxf(S[1][1][0], S[1][1][1]), fmaxf(S[1][1][2], S[1][1][3]));
            mx1 = fmaxf(a1, b1);
        }
        // trigger identical to row-reduced check (__any spans all quads)
        const int doresc = __any((mx0 > m_c[0] + 8.f) || (mx1 > m_c[1] + 8.f));
        float alpha0 = 1.f, alpha1 = 1.f;
        if (doresc) {
            // rare path: full row max via cross-quad shuffles
            float r0 = fmaxf(mx0, __shfl_xor(mx0, 16));
            r0 = fmaxf(r0, __shfl_xor(r0, 32));
            float r1 = fmaxf(mx1, __shfl_xor(mx1, 16));
            r1 = fmaxf(r1, __shfl_xor(r1, 32));
            float mn0 = fmaxf(m_c[0], r0);
            float mn1 = fmaxf(m_c[1], r1);
            alpha0 = __expf(m_c[0] - mn0);
            alpha1 = __expf(m_c[1] - mn1);
            m_c[0] = mn0; m_c[1] = mn1;
        }
        // exp + per-lane l accumulation (NO shuffles)
        half8 pfc[2];
        #pragma unroll
        for (int ct = 0; ct < 2; ++ct) {
            const float mm = m_c[ct];
            float rs = 0.f;
            #pragma unroll
            for (int r = 0; r < 4; ++r) {
                float p0 = __expf(S[0][ct][r] - mm);
                float p1 = __expf(S[1][ct][r] - mm);
                rs += p0 + p1;
                pfc[ct][r]     = (half_t)p0;
                pfc[ct][4 + r] = (half_t)p1;
            }
            l_c[ct] = l_c[ct] * (ct ? alpha1 : alpha0) + rs;
        }
        // rescale AFTER PV(it-1) accumulated (data-dep on ctx regs)
        if (doresc) {
            #pragma unroll
            for (int dt = 0; dt < 16; ++dt)
                #pragma unroll
                for (int r = 0; r < 4; ++r) {
                    ctx[dt][0][r] *= alpha0;
                    ctx[dt][1][r] *= alpha1;
                }
        }
        pfp[0] = pfc[0];
        pfp[1] = pfc[1];
    }

    // drain V(NIT-1) (still in flight) + global cert; final deferred PV.
    asm volatile("s_waitcnt vmcnt(0)" ::: "memory");
    __builtin_amdgcn_s_barrier();
    asm volatile("" ::: "memory");
    {
        half_t* s_v = (half_t*)(smem + 32768 + (((NIT - 1) & 1) << 14));  // V1 @49152
        __builtin_amdgcn_s_setprio(1);
        #pragma unroll
        for (int dt = 0; dt < 16; ++dt) {
            half8 vf = *(const half8*)(s_v + (dt * 16 + l15) * 32 + vslot8);
            ctx[dt][0] = __builtin_amdgcn_mfma_f32_16x16x32_f16(vf, pfp[0], ctx[dt][0], 0, 0, 0);
            ctx[dt][1] = __builtin_amdgcn_mfma_f32_16x16x32_f16(vf, pfp[1], ctx[dt][1], 0, 0, 0);
        }
        __builtin_amdgcn_s_setprio(0);
    }

    // cross-quad l reduction (deferred from the loop; associative)
    float lt[2];
    #pragma unroll
    for (int ct = 0; ct < 2; ++ct) {
        float s = l_c[ct];
        s += __shfl_xor(s, 16);
        s += __shfl_xor(s, 32);
        lt[ct] = s;
    }

    // epilogue: normalized partial context (fp16) via per-wave LDS transpose.
    // scr regions (bytes < 34816) don't overlap V1 (@>=49152) -> safe.
    float rinv[2] = {1.0f / lt[0], 1.0f / lt[1]};
    float* sw = scr + wv * (32 * 68);       // [q 32][stride 68] f32
    half_t* pcs = pc + (size_t)ks * NROWS * 256;
    #pragma unroll
    for (int rd = 0; rd < 4; ++rd) {
        #pragma unroll
        for (int dtl = 0; dtl < 4; ++dtl) {
            const int dt = rd * 4 + dtl;
            #pragma unroll
            for (int ct = 0; ct < 2; ++ct)
                #pragma unroll
                for (int r = 0; r < 4; ++r)
                    sw[(ct * 16 + l15) * 68 + dtl * 16 + quad * 4 + r] = ctx[dt][ct][r] * rinv[ct];
        }
        #pragma unroll
        for (int i = 0; i < 8; ++i) {
            int g = lane + i * 64;
            int q = g >> 4, dc = g & 15;
            float4_ v4 = *(const float4_*)(sw + q * 68 + dc * 4);
            half4v h4;
            #pragma unroll
            for (int j = 0; j < 4; ++j) h4[j] = (half_t)v4[j];
            *(half4v*)(pcs + (size_t)(qbase + q) * 256 + rd * 64 + dc * 4) = h4;
        }
    }
    if (quad == 0) {
        #pragma unroll
        for (int ct = 0; ct < 2; ++ct) {
            const size_t row = qbase + ct * 16 + l15;
            pm[(size_t)ks * NROWS + row] = m_c[ct];
            pl[(size_t)ks * NROWS + row] = lt[ct];
        }
    }
}

// ---------------------------------------------------------------------------
// Kernel 4: merge the KS k-split partials.
// ---------------------------------------------------------------------------
__global__ __launch_bounds__(256) void combine_kernel(
    const half_t* __restrict__ pc, const float* __restrict__ pm,
    const float* __restrict__ pl, float* __restrict__ out)
{
    const int t = threadIdx.x;
    const int row = blockIdx.x * 4 + (t >> 6);
    const int d0 = (t & 63) * 4;
    float m[KS], l[KS];
    float ms = -1e30f;
    #pragma unroll
    for (int i = 0; i < KS; ++i) {
        m[i] = pm[(size_t)i * NROWS + row];
        l[i] = pl[(size_t)i * NROWS + row];
        ms = fmaxf(ms, m[i]);
    }
    float w[KS], tot = 0.f;
    #pragma unroll
    for (int i = 0; i < KS; ++i) {
        w[i] = l[i] * __expf(m[i] - ms);
        tot += w[i];
    }
    float inv = 1.0f / tot;
    float4_ o = {0.f, 0.f, 0.f, 0.f};
    #pragma unroll
    for (int i = 0; i < KS; ++i) {
        half4v y = *(const half4v*)(pc + ((size_t)i * NROWS + row) * 256 + d0);
        float wi = w[i] * inv;
        #pragma unroll
        for (int j = 0; j < 4; ++j) o[j] += wi * (float)y[j];
    }
    *(float4_*)(out + (size_t)row * 256 + d0) = o;
}

// ---------------------------------------------------------------------------
extern "C" void kernel_launch(void* const* d_in, const int* in_sizes, int n_in,
                              void* d_out, int out_size, void* d_ws, size_t ws_size,
                              hipStream_t stream) {
    const float* x      = (const float*)d_in[0];
    const float* states = (const float*)d_in[1];
    const float* Wq     = (const float*)d_in[2];
    const float* bq     = (const float*)d_in[3];
    const float* Wk     = (const float*)d_in[4];
    const float* bk     = (const float*)d_in[5];
    const float* Wv     = (const float*)d_in[6];
    const float* bv     = (const float*)d_in[7];
    const float* Wa     = (const float*)d_in[8];
    // ba (d_in[9]) contributes a per-row constant to scores -> softmax-invariant -> unused.
    float* out = (float*)d_out;

    char* ws = (char*)d_ws;
    size_t off = 0;
    auto alloc = [&](size_t bytes) -> void* {
        void* p = ws + off;
        off += (bytes + 255) & ~(size_t)255;
        return p;
    };
    half_t* M_hi  = (half_t*)alloc(65536 * 2);
    half_t* M_lo  = (half_t*)alloc(65536 * 2);
    half_t* Wk_hi = (half_t*)alloc(65536 * 2);
    half_t* Wk_lo = (half_t*)alloc(65536 * 2);
    half_t* Wv_hi = (half_t*)alloc(65536 * 2);
    float*  bq2   = (float*)alloc(256 * 4);
    half_t* q2_hi = (half_t*)alloc((size_t)NROWS * 256 * 2);
    half_t* k_hi  = (half_t*)alloc((size_t)NROWS * 256 * 2);   // tiled layout
    half_t* vT    = (half_t*)alloc((size_t)NROWS * 256 * 2);   // tiled layout
    half_t* pc    = (half_t*)alloc((size_t)KS * NROWS * 256 * 2);
    float*  pm    = (float*)alloc((size_t)KS * NROWS * 4);
    float*  pl    = (float*)alloc((size_t)KS * NROWS * 4);

    prep_kernel<<<256, 256, 0, stream>>>(Wq, Wk, Wv, Wa, bq,
                                         M_hi, M_lo, Wk_hi, Wk_lo, Wv_hi, bq2);
    linear_kernel<<<768, 256, 0, stream>>>(x, states,
                                           M_hi, M_lo, bq2,
                                           Wk_hi, Wk_lo, bk,
                                           Wv_hi, bv,
                                           q2_hi, k_hi, vT);
    attn_kernel<<<8 * 16 * KS, 256, 0, stream>>>(q2_hi, k_hi, vT,
                                                 pc, pm, pl);
    combine_kernel<<<NROWS / 4, 256, 0, stream>>>(pc, pm, pl, out);
}